// Round 3
// baseline (5979.957 us; speedup 1.0000x reference)
//
#include <hip/hip_runtime.h>
#include <hip/hip_bf16.h>
#include <cstdint>

typedef short v8s __attribute__((ext_vector_type(8)));
typedef float f32x4 __attribute__((ext_vector_type(4)));
typedef float f4 __attribute__((ext_vector_type(4)));

#define BB 512
#define TT 256
#define DD 128
#define HH 512
#define GINW 768
#define LDSP 520   // 512 + 8 bf16 pad: row stride 1040B = 65*16B, 4-bank rotation

static __device__ __forceinline__ unsigned short f2b(float f) {
  __hip_bfloat16 h = __float2bfloat16(f);
  return __builtin_bit_cast(unsigned short, h);
}
static __device__ __forceinline__ unsigned long long pk4(float a, float b, float c, float d) {
  return (unsigned long long)f2b(a) | ((unsigned long long)f2b(b) << 16)
       | ((unsigned long long)f2b(c) << 32) | ((unsigned long long)f2b(d) << 48);
}
static __device__ __forceinline__ float sigm(float v) { return 1.f / (1.f + __expf(-v)); }
static __device__ __forceinline__ float tanh_f(float v) { return 1.f - 2.f / (__expf(2.f * v) + 1.f); }

#define MFMA(A, B, C) __builtin_amdgcn_mfma_f32_16x16x32_bf16((A), (B), (C), 0, 0, 0)

// Single persistent kernel, plain launch, grid = 256 = CU count.
// Co-residency argument (deadlock safety of the group barrier): static LDS
// 62.7KB allows 2 blocks/CU, VGPR <= 512 allows >= 1 block/CU, so device
// capacity >= 256 blocks >= grid — every block is resident from dispatch.
// 16 groups (g = bid&15) x 16 column-slice blocks (j = bid>>4).
// Group g owns batch rows [32g, 32g+32); block (g,j) owns h-columns [32j, 32j+32).
// All gate weights live in VGPRs as MFMA B-fragments (~304 VGPRs).
// Per step: stage x_tilde/mask (t) + delta (t+1) -> x-part GEMMs -> h-part
// z/r GEMMs -> exchange p=r*h via L3 (agent atomics + 16-block counting
// barrier) -> n GEMM -> h update (fp32 own slice) -> exchange decayed h.
__global__ __launch_bounds__(256, 1) void k_seq(
    const float* __restrict__ x, const float* __restrict__ xl,
    const float* __restrict__ mk, const float* __restrict__ de,
    const float* __restrict__ xmean,
    const float* __restrict__ Wz, const float* __restrict__ bz,
    const float* __restrict__ Wr, const float* __restrict__ br,
    const float* __restrict__ Wn, const float* __restrict__ bn,
    const float* __restrict__ Wgx, const float* __restrict__ bgx,
    const float* __restrict__ Wgh, const float* __restrict__ bgh,
    unsigned short* __restrict__ PBUF, unsigned short* __restrict__ HBUF,
    unsigned int* __restrict__ BAR, float* __restrict__ out)
{
  __shared__ unsigned short hp[32 * LDSP];    // staged full h / p tile (bf16)
  __shared__ unsigned short sl[32 * 36];      // own 32x32 slice repack for export
  __shared__ unsigned short XA[32 * 264];     // [x_tilde(128) | m(128)] bf16, pad 8
  __shared__ unsigned short DLs[32 * 136];    // delta(t+1) bf16, pad 8
  __shared__ float cw[128], cbx[128], cxm[128];  // diag(Wgx), bgx, x_mean

  const int bid = blockIdx.x;
  const int g = bid & 15, j = bid >> 4;
  const int tid = threadIdx.x, wave = tid >> 6, lane = tid & 63;
  const int q = lane >> 4, ln = lane & 15;
  const int mh = wave >> 1, nh = wave & 1;
  const int b0 = g * 32, c0 = j * 32;
  const int mrow = mh * 16 + q * 4;          // +rg = local batch row (C layout)
  const int ccol = c0 + nh * 16 + ln;        // global h column this lane owns

  if (tid < 128) { cw[tid] = Wgx[tid * DD + tid]; cbx[tid] = bgx[tid]; cxm[tid] = xmean[tid]; }

  const float bzv = bz[ccol], brv = br[ccol], bnv = bn[ccol], bgv = bgh[ccol];

  // ---- weight fragments (one-time; bf16 in VGPRs) ----
  v8s zb[16], rb[16], nb[16];        // h-part cols [128:640) of GIN, K=512
  {
    const size_t wro = (size_t)ccol * GINW + 128;
#pragma unroll
    for (int ks = 0; ks < 16; ++ks) {
      const float* pz = Wz + wro + ks * 32 + q * 8;
      const float* pr = Wr + wro + ks * 32 + q * 8;
      const float* pn = Wn + wro + ks * 32 + q * 8;
      v8s vz, vr, vn;
#pragma unroll
      for (int e = 0; e < 8; ++e) {
        vz[e] = (short)f2b(pz[e]); vr[e] = (short)f2b(pr[e]); vn[e] = (short)f2b(pn[e]);
      }
      zb[ks] = vz; rb[ks] = vr; nb[ks] = vn;
    }
  }
  v8s xzb[8], xrb[8], xnb[8];        // x-part [0:128) + m-part [640:768), K'=256
  {
    const size_t wro = (size_t)ccol * GINW;
#pragma unroll
    for (int ks = 0; ks < 8; ++ks) {
      const size_t o = wro + ((ks < 4) ? (size_t)(ks * 32 + q * 8) : (size_t)(512 + ks * 32 + q * 8));
      const float* pz = Wz + o; const float* pr = Wr + o; const float* pn = Wn + o;
      v8s vz, vr, vn;
#pragma unroll
      for (int e = 0; e < 8; ++e) {
        vz[e] = (short)f2b(pz[e]); vr[e] = (short)f2b(pr[e]); vn[e] = (short)f2b(pn[e]);
      }
      xzb[ks] = vz; xrb[ks] = vr; xnb[ks] = vn;
    }
  }
  v8s gb[4];                         // Wgh own cols, K=128
  {
    const size_t wro = (size_t)ccol * DD;
#pragma unroll
    for (int ks = 0; ks < 4; ++ks) {
      const float* pg = Wgh + wro + ks * 32 + q * 8;
      v8s vg;
#pragma unroll
      for (int e = 0; e < 8; ++e) vg[e] = (short)f2b(pg[e]);
      gb[ks] = vg;
    }
  }

  for (int i = tid; i < 32 * LDSP / 2; i += 256) ((unsigned int*)hp)[i] = 0u;  // h0 = 0
  float h_own[4] = {0.f, 0.f, 0.f, 0.f};      // fp32 carry, own (rows, col)
  unsigned int bar_t = 0;
  __syncthreads();

  unsigned short* pb = PBUF + (size_t)(g * 2) * 32 * HH;
  unsigned short* hb = HBUF + (size_t)(g * 2) * 32 * HH;
  unsigned int* cnt = BAR + g * 64;           // 256B stride between groups

  const int erow = tid >> 3, ed0 = (tid & 7) * 16;
  const size_t xrowb = (size_t)(b0 + erow) * TT * DD;

  for (int t = 0; t < TT; ++t) {
    const int par = t & 1;
    // ---- elementwise stage: XA for t, DLs (delta) for t+1 ----
    {
      const size_t bt = xrowb + (size_t)t * DD + ed0;
      const int tn = (t + 1 < TT) ? (t + 1) : (TT - 1);
      const size_t bn_ = xrowb + (size_t)tn * DD + ed0;
      const f4* px  = (const f4*)(x + bt);
      const f4* pxl = (const f4*)(xl + bt);
      const f4* pmk = (const f4*)(mk + bt);
      const f4* pdl = (const f4*)(de + bt);
      const f4* pdn = (const f4*)(de + bn_);
#pragma unroll
      for (int c = 0; c < 4; ++c) {
        const int d = ed0 + c * 4;
        f4 wv  = *(const f4*)&cw[d];
        f4 bv  = *(const f4*)&cbx[d];
        f4 xmv = *(const f4*)&cxm[d];
        f4 xv = px[c], xlv = pxl[c], mkv = pmk[c], dv = pdl[c], dnv = pdn[c];
        float xt[4];
#pragma unroll
        for (int e = 0; e < 4; ++e) {
          float gx = __expf(-fmaxf(0.f, dv[e] * wv[e] + bv[e]));
          float q1 = gx * (xlv[e] - xmv[e]) + xmv[e];
          xt[e] = q1 + mkv[e] * (xv[e] - q1);
        }
        *(unsigned long long*)&XA[erow * 264 + d]        = pk4(xt[0], xt[1], xt[2], xt[3]);
        *(unsigned long long*)&XA[erow * 264 + 128 + d]  = pk4(mkv[0], mkv[1], mkv[2], mkv[3]);
        *(unsigned long long*)&DLs[erow * 136 + d]       = pk4(dnv[0], dnv[1], dnv[2], dnv[3]);
      }
    }
    __syncthreads();

    // ---- x/m-part GEMMs + gh GEMM (h-independent) ----
    f32x4 az = {0.f,0.f,0.f,0.f}, ar = {0.f,0.f,0.f,0.f};
    f32x4 an = {0.f,0.f,0.f,0.f}, ag = {0.f,0.f,0.f,0.f};
#pragma unroll
    for (int ks = 0; ks < 8; ++ks) {
      v8s a = *(const v8s*)&XA[(mh * 16 + ln) * 264 + ks * 32 + q * 8];
      az = MFMA(a, xzb[ks], az);
      ar = MFMA(a, xrb[ks], ar);
      an = MFMA(a, xnb[ks], an);
    }
#pragma unroll
    for (int ks = 0; ks < 4; ++ks) {
      v8s a = *(const v8s*)&DLs[(mh * 16 + ln) * 136 + ks * 32 + q * 8];
      ag = MFMA(a, gb[ks], ag);
    }
    // ---- phase A: h-part of z, r ----
#pragma unroll
    for (int ks = 0; ks < 16; ++ks) {
      v8s a = *(const v8s*)&hp[(mh * 16 + ln) * LDSP + ks * 32 + q * 8];
      az = MFMA(a, zb[ks], az);
      ar = MFMA(a, rb[ks], ar);
    }
    float zz[4], ghv[4];
#pragma unroll
    for (int rg = 0; rg < 4; ++rg) {
      float z = sigm(az[rg] + bzv);
      float r = sigm(ar[rg] + brv);
      zz[rg] = z;
      ghv[rg] = __expf(-fmaxf(0.f, ag[rg] + bgv));   // gamma_h for step t+1
      sl[(mrow + rg) * 36 + nh * 16 + ln] = f2b(r * h_own[rg]);
    }
    __syncthreads();
    { // export p slice (own 32 cols) to L3
      int rr = tid >> 3, cq = (tid & 7) * 4;
      unsigned long long v = *(unsigned long long*)&sl[rr * 36 + cq];
      __hip_atomic_store((unsigned long long*)(pb + (size_t)par * 32 * HH + (size_t)rr * HH + c0 + cq),
                         v, __ATOMIC_RELAXED, __HIP_MEMORY_SCOPE_AGENT);
    }
    bar_t += 16;
    __syncthreads();
    if (tid == 0) {
      __hip_atomic_fetch_add(cnt, 1u, __ATOMIC_RELEASE, __HIP_MEMORY_SCOPE_AGENT);
      while (__hip_atomic_load(cnt, __ATOMIC_ACQUIRE, __HIP_MEMORY_SCOPE_AGENT) < bar_t)
        __builtin_amdgcn_s_sleep(1);
    }
    __syncthreads();
    { // stage full p (32x512)
      const unsigned short* src = pb + (size_t)par * 32 * HH;
#pragma unroll
      for (int it = 0; it < 16; ++it) {
        int i = it * 256 + tid; int e = i * 4; int row = e >> 9; int col = e & 511;
        unsigned long long v = __hip_atomic_load(
            (const unsigned long long*)(src + (size_t)row * HH + col),
            __ATOMIC_RELAXED, __HIP_MEMORY_SCOPE_AGENT);
        *(unsigned long long*)&hp[row * LDSP + col] = v;
      }
    }
    __syncthreads();
    // ---- phase B: h-part of n (over p) ----
#pragma unroll
    for (int ks = 0; ks < 16; ++ks) {
      v8s a = *(const v8s*)&hp[(mh * 16 + ln) * LDSP + ks * 32 + q * 8];
      an = MFMA(a, nb[ks], an);
    }
    if (t == TT - 1) {
#pragma unroll
      for (int rg = 0; rg < 4; ++rg) {
        float n = tanh_f(an[rg] + bnv);
        out[(size_t)(b0 + mrow + rg) * HH + ccol] = (1.f - zz[rg]) * h_own[rg] + zz[rg] * n;
      }
    } else {
#pragma unroll
      for (int rg = 0; rg < 4; ++rg) {
        float n = tanh_f(an[rg] + bnv);
        float hn = (1.f - zz[rg]) * h_own[rg] + zz[rg] * n;
        float hd = ghv[rg] * hn;                     // pre-apply next step's decay
        h_own[rg] = hd;
        sl[(mrow + rg) * 36 + nh * 16 + ln] = f2b(hd);
      }
      __syncthreads();
      { // export decayed h slice
        int rr = tid >> 3, cq = (tid & 7) * 4;
        unsigned long long v = *(unsigned long long*)&sl[rr * 36 + cq];
        __hip_atomic_store((unsigned long long*)(hb + (size_t)par * 32 * HH + (size_t)rr * HH + c0 + cq),
                           v, __ATOMIC_RELAXED, __HIP_MEMORY_SCOPE_AGENT);
      }
      bar_t += 16;
      __syncthreads();
      if (tid == 0) {
        __hip_atomic_fetch_add(cnt, 1u, __ATOMIC_RELEASE, __HIP_MEMORY_SCOPE_AGENT);
        while (__hip_atomic_load(cnt, __ATOMIC_ACQUIRE, __HIP_MEMORY_SCOPE_AGENT) < bar_t)
          __builtin_amdgcn_s_sleep(1);
      }
      __syncthreads();
      { // stage full decayed h for next step
        const unsigned short* src = hb + (size_t)par * 32 * HH;
#pragma unroll
        for (int it = 0; it < 16; ++it) {
          int i = it * 256 + tid; int e = i * 4; int row = e >> 9; int col = e & 511;
          unsigned long long v = __hip_atomic_load(
              (const unsigned long long*)(src + (size_t)row * HH + col),
              __ATOMIC_RELAXED, __HIP_MEMORY_SCOPE_AGENT);
          *(unsigned long long*)&hp[row * LDSP + col] = v;
        }
      }
      __syncthreads();
    }
  }
}

extern "C" void kernel_launch(void* const* d_in, const int* in_sizes, int n_in,
                              void* d_out, int out_size, void* d_ws, size_t ws_size,
                              hipStream_t stream)
{
  const float* x   = (const float*)d_in[0];
  const float* xl  = (const float*)d_in[1];
  const float* mk  = (const float*)d_in[2];
  const float* de  = (const float*)d_in[3];
  const float* xm  = (const float*)d_in[4];
  const float* Wz  = (const float*)d_in[5];
  const float* bz  = (const float*)d_in[6];
  const float* Wr  = (const float*)d_in[7];
  const float* br  = (const float*)d_in[8];
  const float* Wn  = (const float*)d_in[9];
  const float* bn  = (const float*)d_in[10];
  const float* Wgx = (const float*)d_in[11];
  const float* bgx = (const float*)d_in[12];
  const float* Wgh = (const float*)d_in[13];
  const float* bgh = (const float*)d_in[14];
  float* out = (float*)d_out;

  char* p = (char*)d_ws;
  auto take = [&](size_t bytes) { char* r = p; p += (bytes + 255) & ~(size_t)255; return r; };
  unsigned short* PBUF = (unsigned short*)take((size_t)16 * 2 * 32 * HH * 2);  // 1 MB
  unsigned short* HBUF = (unsigned short*)take((size_t)16 * 2 * 32 * HH * 2);  // 1 MB
  unsigned int*   BARp = (unsigned int*)take(16 * 256);                        // 4 KB

  hipMemsetAsync(BARp, 0, 16 * 256, stream);

  // Plain launch (cooperative launch was a silent no-op in R2). Grid = 256
  // blocks <= device capacity (LDS 62.7KB -> 2 blocks/CU; VGPR <= 512 ->
  // >= 1 block/CU), so all blocks are co-resident: group barrier is safe.
  k_seq<<<dim3(256), dim3(256), 0, stream>>>(
      x, xl, mk, de, xm, Wz, bz, Wr, br, Wn, bn,
      Wgx, bgx, Wgh, bgh, PBUF, HBUF, BARp, out);

  (void)in_sizes; (void)n_in; (void)out_size; (void)ws_size;
}

// Round 4
// 4162.284 us; speedup vs baseline: 1.4367x; 1.4367x over previous
//
#include <hip/hip_runtime.h>
#include <hip/hip_bf16.h>
#include <cstdint>

typedef short v8s __attribute__((ext_vector_type(8)));
typedef float f32x4 __attribute__((ext_vector_type(4)));
typedef float f4 __attribute__((ext_vector_type(4)));

#define BB 512
#define TT 256
#define DD 128
#define HH 512
#define GINW 768
#define LDSP 520   // 512 + 8 bf16 pad

static __device__ __forceinline__ unsigned short f2b(float f) {
  __hip_bfloat16 h = __float2bfloat16(f);
  return __builtin_bit_cast(unsigned short, h);
}
static __device__ __forceinline__ unsigned long long pk4(float a, float b, float c, float d) {
  return (unsigned long long)f2b(a) | ((unsigned long long)f2b(b) << 16)
       | ((unsigned long long)f2b(c) << 32) | ((unsigned long long)f2b(d) << 48);
}
static __device__ __forceinline__ float sigm(float v) { return 1.f / (1.f + __expf(-v)); }
static __device__ __forceinline__ float tanh_f(float v) { return 1.f - 2.f / (__expf(2.f * v) + 1.f); }

#define MFMA(A, B, C) __builtin_amdgcn_mfma_f32_16x16x32_bf16((A), (B), (C), 0, 0, 0)

// Single persistent kernel, plain launch, grid = 256 = CU count.
// Co-residency (barrier safety): static LDS 61.5KB -> <=2 blocks/CU; VGPR<=512
// -> >=1 block/CU; capacity >= 256 blocks >= grid, so all blocks resident.
// 16 groups (g=bid&15) x 16 column-slices (j=bid>>4). Group g owns batch rows
// [32g,32g+32); block (g,j) owns h-columns [32j,32j+32). Weights in VGPRs.
// Barrier: per-block epoch flags, ALL RELAXED agent atomics (no acq/rel =>
// no buffer_wbl2 / buffer_inv L2 maintenance, no RMW serialization).
// Data exchange: relaxed agent atomic 8B stores/loads (L2-bypass, L3-coherent)
// — correctness of this primitive proven by R3 pass.
__global__ __launch_bounds__(256, 1) void k_seq(
    const float* __restrict__ x, const float* __restrict__ xl,
    const float* __restrict__ mk, const float* __restrict__ de,
    const float* __restrict__ xmean,
    const float* __restrict__ Wz, const float* __restrict__ bz,
    const float* __restrict__ Wr, const float* __restrict__ br,
    const float* __restrict__ Wn, const float* __restrict__ bn,
    const float* __restrict__ Wgx, const float* __restrict__ bgx,
    const float* __restrict__ Wgh, const float* __restrict__ bgh,
    unsigned short* __restrict__ PBUF, unsigned short* __restrict__ HBUF,
    unsigned int* __restrict__ BAR, float* __restrict__ out)
{
  __shared__ unsigned short hp[32 * LDSP];    // staged full h / p tile (bf16)
  __shared__ unsigned short sl[32 * 36];      // own 32x32 slice repack for export
  __shared__ unsigned short XA[32 * 264];     // [x_tilde(128) | m(128)] bf16
  __shared__ unsigned short DLs[32 * 136];    // delta(t+1) bf16
  __shared__ float cw[128], cbx[128], cxm[128];

  const int bid = blockIdx.x;
  const int g = bid & 15, j = bid >> 4;
  const int tid = threadIdx.x, wave = tid >> 6, lane = tid & 63;
  const int q = lane >> 4, ln = lane & 15;
  const int mh = wave >> 1, nh = wave & 1;
  const int b0 = g * 32, c0 = j * 32;
  const int mrow = mh * 16 + q * 4;
  const int ccol = c0 + nh * 16 + ln;

  if (tid < 128) { cw[tid] = Wgx[tid * DD + tid]; cbx[tid] = bgx[tid]; cxm[tid] = xmean[tid]; }

  const float bzv = bz[ccol], brv = br[ccol], bnv = bn[ccol], bgv = bgh[ccol];

  // ---- weight fragments (one-time; bf16 in VGPRs) ----
  v8s zb[16], rb[16], nb[16];        // h-part cols [128:640) of GIN, K=512
  {
    const size_t wro = (size_t)ccol * GINW + 128;
#pragma unroll
    for (int ks = 0; ks < 16; ++ks) {
      const float* pz = Wz + wro + ks * 32 + q * 8;
      const float* pr = Wr + wro + ks * 32 + q * 8;
      const float* pn = Wn + wro + ks * 32 + q * 8;
      v8s vz, vr, vn;
#pragma unroll
      for (int e = 0; e < 8; ++e) {
        vz[e] = (short)f2b(pz[e]); vr[e] = (short)f2b(pr[e]); vn[e] = (short)f2b(pn[e]);
      }
      zb[ks] = vz; rb[ks] = vr; nb[ks] = vn;
    }
  }
  v8s xzb[8], xrb[8], xnb[8];        // x-part [0:128) + m-part [640:768), K'=256
  {
    const size_t wro = (size_t)ccol * GINW;
#pragma unroll
    for (int ks = 0; ks < 8; ++ks) {
      const size_t o = wro + ((ks < 4) ? (size_t)(ks * 32 + q * 8) : (size_t)(512 + ks * 32 + q * 8));
      const float* pz = Wz + o; const float* pr = Wr + o; const float* pn = Wn + o;
      v8s vz, vr, vn;
#pragma unroll
      for (int e = 0; e < 8; ++e) {
        vz[e] = (short)f2b(pz[e]); vr[e] = (short)f2b(pr[e]); vn[e] = (short)f2b(pn[e]);
      }
      xzb[ks] = vz; xrb[ks] = vr; xnb[ks] = vn;
    }
  }
  v8s gb[4];                         // Wgh own cols, K=128
  {
    const size_t wro = (size_t)ccol * DD;
#pragma unroll
    for (int ks = 0; ks < 4; ++ks) {
      const float* pg = Wgh + wro + ks * 32 + q * 8;
      v8s vg;
#pragma unroll
      for (int e = 0; e < 8; ++e) vg[e] = (short)f2b(pg[e]);
      gb[ks] = vg;
    }
  }

  for (int i = tid; i < 32 * LDSP / 2; i += 256) ((unsigned int*)hp)[i] = 0u;  // h0 = 0
  float h_own[4] = {0.f, 0.f, 0.f, 0.f};
  unsigned int ep = 0;                        // barrier epoch (monotone)
  __syncthreads();

  unsigned short* pb = PBUF + (size_t)(g * 2) * 32 * HH;
  unsigned short* hb = HBUF + (size_t)(g * 2) * 32 * HH;
  unsigned int* flg = BAR + g * 64;           // 16 flags @ 16B stride per group
  unsigned int* myf = flg + j * 4;

  const int erow = tid >> 3, ed0 = (tid & 7) * 16;
  const size_t xrowb = (size_t)(b0 + erow) * TT * DD;

  // relaxed-flag group barrier: caller must have drained data stores
  // (__syncthreads auto-inserts s_waitcnt vmcnt(0) before s_barrier).
#define GROUP_BARRIER()                                                        \
  do {                                                                         \
    ++ep;                                                                      \
    __syncthreads();        /* drains all waves' exports to L3 */              \
    if (tid == 0)                                                              \
      __hip_atomic_store(myf, ep, __ATOMIC_RELAXED, __HIP_MEMORY_SCOPE_AGENT); \
    asm volatile("" ::: "memory");                                             \
    if (tid < 16 && tid != j) {                                                \
      const unsigned int* fp = flg + tid * 4;                                  \
      while (__hip_atomic_load(fp, __ATOMIC_RELAXED,                           \
                               __HIP_MEMORY_SCOPE_AGENT) < ep) {}              \
    }                                                                          \
    __syncthreads();                                                           \
  } while (0)

  for (int t = 0; t < TT; ++t) {
    const int par = t & 1;
    // ---- elementwise stage: XA for t, DLs (delta) for t+1 ----
    {
      const size_t bt = xrowb + (size_t)t * DD + ed0;
      const int tn = (t + 1 < TT) ? (t + 1) : (TT - 1);
      const size_t bn_ = xrowb + (size_t)tn * DD + ed0;
      const f4* px  = (const f4*)(x + bt);
      const f4* pxl = (const f4*)(xl + bt);
      const f4* pmk = (const f4*)(mk + bt);
      const f4* pdl = (const f4*)(de + bt);
      const f4* pdn = (const f4*)(de + bn_);
#pragma unroll
      for (int c = 0; c < 4; ++c) {
        const int d = ed0 + c * 4;
        f4 wv  = *(const f4*)&cw[d];
        f4 bv  = *(const f4*)&cbx[d];
        f4 xmv = *(const f4*)&cxm[d];
        f4 xv = px[c], xlv = pxl[c], mkv = pmk[c], dv = pdl[c], dnv = pdn[c];
        float xt[4];
#pragma unroll
        for (int e = 0; e < 4; ++e) {
          float gx = __expf(-fmaxf(0.f, dv[e] * wv[e] + bv[e]));
          float q1 = gx * (xlv[e] - xmv[e]) + xmv[e];
          xt[e] = q1 + mkv[e] * (xv[e] - q1);
        }
        *(unsigned long long*)&XA[erow * 264 + d]        = pk4(xt[0], xt[1], xt[2], xt[3]);
        *(unsigned long long*)&XA[erow * 264 + 128 + d]  = pk4(mkv[0], mkv[1], mkv[2], mkv[3]);
        *(unsigned long long*)&DLs[erow * 136 + d]       = pk4(dnv[0], dnv[1], dnv[2], dnv[3]);
      }
    }
    __syncthreads();

    // ---- x/m-part GEMMs + gh GEMM (h-independent) ----
    f32x4 az = {0.f,0.f,0.f,0.f}, ar = {0.f,0.f,0.f,0.f};
    f32x4 an = {0.f,0.f,0.f,0.f}, ag = {0.f,0.f,0.f,0.f};
#pragma unroll
    for (int ks = 0; ks < 8; ++ks) {
      v8s a = *(const v8s*)&XA[(mh * 16 + ln) * 264 + ks * 32 + q * 8];
      az = MFMA(a, xzb[ks], az);
      ar = MFMA(a, xrb[ks], ar);
      an = MFMA(a, xnb[ks], an);
    }
#pragma unroll
    for (int ks = 0; ks < 4; ++ks) {
      v8s a = *(const v8s*)&DLs[(mh * 16 + ln) * 136 + ks * 32 + q * 8];
      ag = MFMA(a, gb[ks], ag);
    }
    // ---- phase A: h-part of z, r ----
#pragma unroll
    for (int ks = 0; ks < 16; ++ks) {
      v8s a = *(const v8s*)&hp[(mh * 16 + ln) * LDSP + ks * 32 + q * 8];
      az = MFMA(a, zb[ks], az);
      ar = MFMA(a, rb[ks], ar);
    }
    float zz[4], ghv[4];
#pragma unroll
    for (int rg = 0; rg < 4; ++rg) {
      float z = sigm(az[rg] + bzv);
      float r = sigm(ar[rg] + brv);
      zz[rg] = z;
      ghv[rg] = __expf(-fmaxf(0.f, ag[rg] + bgv));   // gamma_h for step t+1
      sl[(mrow + rg) * 36 + nh * 16 + ln] = f2b(r * h_own[rg]);
    }
    __syncthreads();
    { // export p slice (own 32 cols) to L3
      int rr = tid >> 3, cq = (tid & 7) * 4;
      unsigned long long v = *(unsigned long long*)&sl[rr * 36 + cq];
      __hip_atomic_store((unsigned long long*)(pb + (size_t)par * 32 * HH + (size_t)rr * HH + c0 + cq),
                         v, __ATOMIC_RELAXED, __HIP_MEMORY_SCOPE_AGENT);
    }
    GROUP_BARRIER();
    { // stage full p (32x512)
      const unsigned short* src = pb + (size_t)par * 32 * HH;
#pragma unroll
      for (int it = 0; it < 16; ++it) {
        int i = it * 256 + tid; int e = i * 4; int row = e >> 9; int col = e & 511;
        unsigned long long v = __hip_atomic_load(
            (const unsigned long long*)(src + (size_t)row * HH + col),
            __ATOMIC_RELAXED, __HIP_MEMORY_SCOPE_AGENT);
        *(unsigned long long*)&hp[row * LDSP + col] = v;
      }
    }
    __syncthreads();
    // ---- phase B: h-part of n (over p) ----
#pragma unroll
    for (int ks = 0; ks < 16; ++ks) {
      v8s a = *(const v8s*)&hp[(mh * 16 + ln) * LDSP + ks * 32 + q * 8];
      an = MFMA(a, nb[ks], an);
    }
    if (t == TT - 1) {
#pragma unroll
      for (int rg = 0; rg < 4; ++rg) {
        float n = tanh_f(an[rg] + bnv);
        out[(size_t)(b0 + mrow + rg) * HH + ccol] = (1.f - zz[rg]) * h_own[rg] + zz[rg] * n;
      }
    } else {
#pragma unroll
      for (int rg = 0; rg < 4; ++rg) {
        float n = tanh_f(an[rg] + bnv);
        float hn = (1.f - zz[rg]) * h_own[rg] + zz[rg] * n;
        float hd = ghv[rg] * hn;                     // pre-apply next step's decay
        h_own[rg] = hd;
        sl[(mrow + rg) * 36 + nh * 16 + ln] = f2b(hd);
      }
      __syncthreads();
      { // export decayed h slice
        int rr = tid >> 3, cq = (tid & 7) * 4;
        unsigned long long v = *(unsigned long long*)&sl[rr * 36 + cq];
        __hip_atomic_store((unsigned long long*)(hb + (size_t)par * 32 * HH + (size_t)rr * HH + c0 + cq),
                           v, __ATOMIC_RELAXED, __HIP_MEMORY_SCOPE_AGENT);
      }
      GROUP_BARRIER();
      { // stage full decayed h for next step
        const unsigned short* src = hb + (size_t)par * 32 * HH;
#pragma unroll
        for (int it = 0; it < 16; ++it) {
          int i = it * 256 + tid; int e = i * 4; int row = e >> 9; int col = e & 511;
          unsigned long long v = __hip_atomic_load(
              (const unsigned long long*)(src + (size_t)row * HH + col),
              __ATOMIC_RELAXED, __HIP_MEMORY_SCOPE_AGENT);
          *(unsigned long long*)&hp[row * LDSP + col] = v;
        }
      }
      __syncthreads();
    }
  }
#undef GROUP_BARRIER
}

extern "C" void kernel_launch(void* const* d_in, const int* in_sizes, int n_in,
                              void* d_out, int out_size, void* d_ws, size_t ws_size,
                              hipStream_t stream)
{
  const float* x   = (const float*)d_in[0];
  const float* xl  = (const float*)d_in[1];
  const float* mk  = (const float*)d_in[2];
  const float* de  = (const float*)d_in[3];
  const float* xm  = (const float*)d_in[4];
  const float* Wz  = (const float*)d_in[5];
  const float* bz  = (const float*)d_in[6];
  const float* Wr  = (const float*)d_in[7];
  const float* br  = (const float*)d_in[8];
  const float* Wn  = (const float*)d_in[9];
  const float* bn  = (const float*)d_in[10];
  const float* Wgx = (const float*)d_in[11];
  const float* bgx = (const float*)d_in[12];
  const float* Wgh = (const float*)d_in[13];
  const float* bgh = (const float*)d_in[14];
  float* out = (float*)d_out;

  char* p = (char*)d_ws;
  auto take = [&](size_t bytes) { char* r = p; p += (bytes + 255) & ~(size_t)255; return r; };
  unsigned short* PBUF = (unsigned short*)take((size_t)16 * 2 * 32 * HH * 2);  // 1 MB
  unsigned short* HBUF = (unsigned short*)take((size_t)16 * 2 * 32 * HH * 2);  // 1 MB
  unsigned int*   BARp = (unsigned int*)take(16 * 256);                        // 4 KB

  hipMemsetAsync(BARp, 0, 16 * 256, stream);

  k_seq<<<dim3(256), dim3(256), 0, stream>>>(
      x, xl, mk, de, xm, Wz, bz, Wr, br, Wn, bn,
      Wgx, bgx, Wgh, bgh, PBUF, HBUF, BARp, out);

  (void)in_sizes; (void)n_in; (void)out_size; (void)ws_size;
}

// Round 5
// 3436.616 us; speedup vs baseline: 1.7401x; 1.2112x over previous
//
#include <hip/hip_runtime.h>
#include <hip/hip_bf16.h>
#include <cstdint>

typedef short v8s __attribute__((ext_vector_type(8)));
typedef float f32x4 __attribute__((ext_vector_type(4)));
typedef float f4 __attribute__((ext_vector_type(4)));

#define BB 512
#define TT 256
#define DD 128
#define HH 512
#define GINW 768

static __device__ __forceinline__ unsigned short f2b(float f) {
  __hip_bfloat16 h = __float2bfloat16(f);
  return __builtin_bit_cast(unsigned short, h);
}
static __device__ __forceinline__ unsigned long long pk4(float a, float b, float c, float d) {
  return (unsigned long long)f2b(a) | ((unsigned long long)f2b(b) << 16)
       | ((unsigned long long)f2b(c) << 32) | ((unsigned long long)f2b(d) << 48);
}
static __device__ __forceinline__ float sigm(float v) { return 1.f / (1.f + __expf(-v)); }
static __device__ __forceinline__ float tanh_f(float v) { return 1.f - 2.f / (__expf(2.f * v) + 1.f); }

#define MFMA(A, B, C) __builtin_amdgcn_mfma_f32_16x16x32_bf16((A), (B), (C), 0, 0, 0)

// Load 16 A-fragments (K=512) for this lane DIRECTLY from the L3-coherent
// exchange buffer into registers. All 32 8B loads are issued into independent
// registers before any use -> they pipeline (one latency, not 32).
static __device__ __forceinline__ void load_frags16(const unsigned short* base, v8s fr[16]) {
  unsigned long long u[32];
#pragma unroll
  for (int ks = 0; ks < 16; ++ks) {
    u[2 * ks]     = __hip_atomic_load((const unsigned long long*)(base + ks * 32),
                                      __ATOMIC_RELAXED, __HIP_MEMORY_SCOPE_AGENT);
    u[2 * ks + 1] = __hip_atomic_load((const unsigned long long*)(base + ks * 32 + 4),
                                      __ATOMIC_RELAXED, __HIP_MEMORY_SCOPE_AGENT);
  }
#pragma unroll
  for (int ks = 0; ks < 16; ++ks) {
    struct P { unsigned long long a, b; } p { u[2 * ks], u[2 * ks + 1] };
    fr[ks] = __builtin_bit_cast(v8s, p);
  }
}

// Persistent kernel, plain launch, grid = 256 = CU count.
// Co-residency (barrier safety): LDS ~55KB -> <=2 blocks/CU; VGPR<=512 -> >=1
// block/CU; capacity >= 256 blocks >= grid => all blocks resident.
// 16 groups (g=bid&15) x 16 column-slices (j=bid>>4); group g owns batch rows
// [32g,32g+32); block (g,j) owns h-cols [32j,32j+32). Weights in VGPRs.
// Exchange: relaxed agent 8B atomics (L3-coherent, proven R3/R4). Barrier:
// relaxed per-block epoch flags. Waits overlapped: p-wait absorbs elementwise
// staging of t+1; h-wait absorbs x-part MFMAs of t+1. A-fragments for the
// h-GEMMs load straight from L3 (row-major == A-frag layout), no LDS staging.
__global__ __launch_bounds__(256, 1) void k_seq(
    const float* __restrict__ x, const float* __restrict__ xl,
    const float* __restrict__ mk, const float* __restrict__ de,
    const float* __restrict__ xmean,
    const float* __restrict__ Wz, const float* __restrict__ bz,
    const float* __restrict__ Wr, const float* __restrict__ br,
    const float* __restrict__ Wn, const float* __restrict__ bn,
    const float* __restrict__ Wgx, const float* __restrict__ bgx,
    const float* __restrict__ Wgh, const float* __restrict__ bgh,
    unsigned short* __restrict__ PBUF, unsigned short* __restrict__ HBUF,
    unsigned int* __restrict__ BAR, float* __restrict__ out)
{
  __shared__ unsigned short XA[2][32 * 264];   // [x_tilde(128)|m(128)] bf16 double-buf
  __shared__ unsigned short DLs[2][32 * 136];  // delta(t+1) bf16 double-buf
  __shared__ unsigned short sl[32 * 36];       // own 32x32 slice repack for export
  __shared__ float cw[128], cbx[128], cxm[128];

  const int bid = blockIdx.x;
  const int g = bid & 15, j = bid >> 4;
  const int tid = threadIdx.x, wave = tid >> 6, lane = tid & 63;
  const int q = lane >> 4, ln = lane & 15;
  const int mh = wave >> 1, nh = wave & 1;
  const int b0 = g * 32, c0 = j * 32;
  const int mrow = mh * 16 + q * 4;            // +rg = local batch row (C layout)
  const int arow = mh * 16 + ln;               // A-fragment row
  const int ccol = c0 + nh * 16 + ln;          // global h column this lane owns

  if (tid < 128) { cw[tid] = Wgx[tid * DD + tid]; cbx[tid] = bgx[tid]; cxm[tid] = xmean[tid]; }

  const float bzv = bz[ccol], brv = br[ccol], bnv = bn[ccol], bgv = bgh[ccol];

  // ---- weight fragments (one-time; bf16 in VGPRs) ----
  v8s zb[16], rb[16], nb[16];        // h-part cols [128:640) of GIN, K=512
  {
    const size_t wro = (size_t)ccol * GINW + 128;
#pragma unroll
    for (int ks = 0; ks < 16; ++ks) {
      const float* pz = Wz + wro + ks * 32 + q * 8;
      const float* pr = Wr + wro + ks * 32 + q * 8;
      const float* pn = Wn + wro + ks * 32 + q * 8;
      v8s vz, vr, vn;
#pragma unroll
      for (int e = 0; e < 8; ++e) {
        vz[e] = (short)f2b(pz[e]); vr[e] = (short)f2b(pr[e]); vn[e] = (short)f2b(pn[e]);
      }
      zb[ks] = vz; rb[ks] = vr; nb[ks] = vn;
    }
  }
  v8s xzb[8], xrb[8], xnb[8];        // x-part [0:128) + m-part [640:768), K'=256
  {
    const size_t wro = (size_t)ccol * GINW;
#pragma unroll
    for (int ks = 0; ks < 8; ++ks) {
      const size_t o = wro + ((ks < 4) ? (size_t)(ks * 32 + q * 8) : (size_t)(512 + ks * 32 + q * 8));
      const float* pz = Wz + o; const float* pr = Wr + o; const float* pn = Wn + o;
      v8s vz, vr, vn;
#pragma unroll
      for (int e = 0; e < 8; ++e) {
        vz[e] = (short)f2b(pz[e]); vr[e] = (short)f2b(pr[e]); vn[e] = (short)f2b(pn[e]);
      }
      xzb[ks] = vz; xrb[ks] = vr; xnb[ks] = vn;
    }
  }
  v8s gb[4];                         // Wgh own cols, K=128
  {
    const size_t wro = (size_t)ccol * DD;
#pragma unroll
    for (int ks = 0; ks < 4; ++ks) {
      const float* pg = Wgh + wro + ks * 32 + q * 8;
      v8s vg;
#pragma unroll
      for (int e = 0; e < 8; ++e) vg[e] = (short)f2b(pg[e]);
      gb[ks] = vg;
    }
  }

  float h_own[4] = {0.f, 0.f, 0.f, 0.f};
  unsigned int ep = 0;
  unsigned short* pb = PBUF + (size_t)(g * 2) * 32 * HH;
  unsigned short* hb = HBUF + (size_t)(g * 2) * 32 * HH;
  unsigned int* flg = BAR + g * 64;            // 16 flags @ 16B stride per group
  unsigned int* myf = flg + j * 4;

  const int erow = tid >> 3, ed0 = (tid & 7) * 16;
  const size_t xrowb = (size_t)(b0 + erow) * TT * DD;

  // ---- elementwise staging of XA(tx), DL=delta(tx+1) into buffer bp ----
  auto stage = [&](int bp, int tx) {
    const size_t bt = xrowb + (size_t)tx * DD + ed0;
    const int tn = (tx + 1 < TT) ? (tx + 1) : (TT - 1);
    const size_t bn_ = xrowb + (size_t)tn * DD + ed0;
    const f4* px  = (const f4*)(x + bt);
    const f4* pxl = (const f4*)(xl + bt);
    const f4* pmk = (const f4*)(mk + bt);
    const f4* pdl = (const f4*)(de + bt);
    const f4* pdn = (const f4*)(de + bn_);
#pragma unroll
    for (int c = 0; c < 4; ++c) {
      const int d = ed0 + c * 4;
      f4 wv  = *(const f4*)&cw[d];
      f4 bv  = *(const f4*)&cbx[d];
      f4 xmv = *(const f4*)&cxm[d];
      f4 xv = px[c], xlv = pxl[c], mkv = pmk[c], dv = pdl[c], dnv = pdn[c];
      float xt[4];
#pragma unroll
      for (int e = 0; e < 4; ++e) {
        float gx = __expf(-fmaxf(0.f, dv[e] * wv[e] + bv[e]));
        float q1 = gx * (xlv[e] - xmv[e]) + xmv[e];
        xt[e] = q1 + mkv[e] * (xv[e] - q1);
      }
      *(unsigned long long*)&XA[bp][erow * 264 + d]       = pk4(xt[0], xt[1], xt[2], xt[3]);
      *(unsigned long long*)&XA[bp][erow * 264 + 128 + d] = pk4(mkv[0], mkv[1], mkv[2], mkv[3]);
      *(unsigned long long*)&DLs[bp][erow * 136 + d]      = pk4(dnv[0], dnv[1], dnv[2], dnv[3]);
    }
  };

  // x-part GEMMs over buffer bp -> fresh accumulators
  f32x4 azc, arc, anc, agc;
  auto xgemm = [&](int bp) {
    f32x4 z_ = {0.f,0.f,0.f,0.f}, r_ = {0.f,0.f,0.f,0.f};
    f32x4 n_ = {0.f,0.f,0.f,0.f}, g_ = {0.f,0.f,0.f,0.f};
#pragma unroll
    for (int ks = 0; ks < 8; ++ks) {
      v8s a = *(const v8s*)&XA[bp][arow * 264 + ks * 32 + q * 8];
      z_ = MFMA(a, xzb[ks], z_);
      r_ = MFMA(a, xrb[ks], r_);
      n_ = MFMA(a, xnb[ks], n_);
    }
#pragma unroll
    for (int ks = 0; ks < 4; ++ks) {
      v8s a = *(const v8s*)&DLs[bp][arow * 136 + ks * 32 + q * 8];
      g_ = MFMA(a, gb[ks], g_);
    }
    azc = z_; arc = r_; anc = n_; agc = g_;
  };

  auto export_sl = [&](unsigned short* dst) {   // dst = group buf + parity offset
    int rr = tid >> 3, cq = (tid & 7) * 4;
    unsigned long long v = *(unsigned long long*)&sl[rr * 36 + cq];
    __hip_atomic_store((unsigned long long*)(dst + (size_t)rr * HH + c0 + cq),
                       v, __ATOMIC_RELAXED, __HIP_MEMORY_SCOPE_AGENT);
  };
  auto poll = [&]() {
    if (tid < 16 && tid != j) {
      const unsigned int* fp = flg + tid * 4;
      while (__hip_atomic_load(fp, __ATOMIC_RELAXED, __HIP_MEMORY_SCOPE_AGENT) < ep) {}
    }
  };

  // ---- prologue: stage t=0, compute its x-part ----
  stage(0, 0);
  __syncthreads();
  xgemm(0);

  for (int t = 0; t < TT; ++t) {
    const int par = t & 1;
    // ---- phase A: h-part of z, r (frags direct from L3) ----
    if (t > 0) {
      v8s fr[16];
      load_frags16(hb + (size_t)((t - 1) & 1) * 32 * HH + (size_t)arow * HH + q * 8, fr);
#pragma unroll
      for (int ks = 0; ks < 16; ++ks) {
        azc = MFMA(fr[ks], zb[ks], azc);
        arc = MFMA(fr[ks], rb[ks], arc);
      }
    }
    float zz[4];
#pragma unroll
    for (int rg = 0; rg < 4; ++rg) {
      float z = sigm(azc[rg] + bzv);
      float r = sigm(arc[rg] + brv);
      zz[rg] = z;
      sl[(mrow + rg) * 36 + nh * 16 + ln] = f2b(r * h_own[rg]);
    }
    // ---- p-barrier (skip at t=0: p==0, all blocks agree) ----
    if (t > 0) {
      __syncthreads();                 // sl visible
      export_sl(pb + (size_t)par * 32 * HH);
      ++ep;
      __syncthreads();                 // drains exports (vmcnt0 before s_barrier)
      if (tid == 0)
        __hip_atomic_store(myf, ep, __ATOMIC_RELAXED, __HIP_MEMORY_SCOPE_AGENT);
    }
    if (t < TT - 1) stage(par ^ 1, t + 1);   // overlaps flag propagation
    if (t > 0) poll();
    __syncthreads();
    // ---- phase B: h-part of n over p ----
    if (t > 0) {
      v8s fr[16];
      load_frags16(pb + (size_t)par * 32 * HH + (size_t)arow * HH + q * 8, fr);
#pragma unroll
      for (int ks = 0; ks < 16; ++ks) anc = MFMA(fr[ks], nb[ks], anc);
    }
    if (t == TT - 1) {
#pragma unroll
      for (int rg = 0; rg < 4; ++rg) {
        float n = tanh_f(anc[rg] + bnv);
        out[(size_t)(b0 + mrow + rg) * HH + ccol] = (1.f - zz[rg]) * h_own[rg] + zz[rg] * n;
      }
    } else {
#pragma unroll
      for (int rg = 0; rg < 4; ++rg) {
        float n = tanh_f(anc[rg] + bnv);
        float hn = (1.f - zz[rg]) * h_own[rg] + zz[rg] * n;
        float hd = __expf(-fmaxf(0.f, agc[rg] + bgv)) * hn;  // pre-apply gamma_h(t+1)
        h_own[rg] = hd;
        sl[(mrow + rg) * 36 + nh * 16 + ln] = f2b(hd);
      }
      __syncthreads();                 // sl visible
      export_sl(hb + (size_t)par * 32 * HH);
      ++ep;
      __syncthreads();                 // drain exports
      if (tid == 0)
        __hip_atomic_store(myf, ep, __ATOMIC_RELAXED, __HIP_MEMORY_SCOPE_AGENT);
      xgemm(par ^ 1);                  // x-part for t+1, overlaps flag propagation
      poll();
      __syncthreads();
    }
  }
}

extern "C" void kernel_launch(void* const* d_in, const int* in_sizes, int n_in,
                              void* d_out, int out_size, void* d_ws, size_t ws_size,
                              hipStream_t stream)
{
  const float* x   = (const float*)d_in[0];
  const float* xl  = (const float*)d_in[1];
  const float* mk  = (const float*)d_in[2];
  const float* de  = (const float*)d_in[3];
  const float* xm  = (const float*)d_in[4];
  const float* Wz  = (const float*)d_in[5];
  const float* bz  = (const float*)d_in[6];
  const float* Wr  = (const float*)d_in[7];
  const float* br  = (const float*)d_in[8];
  const float* Wn  = (const float*)d_in[9];
  const float* bn  = (const float*)d_in[10];
  const float* Wgx = (const float*)d_in[11];
  const float* bgx = (const float*)d_in[12];
  const float* Wgh = (const float*)d_in[13];
  const float* bgh = (const float*)d_in[14];
  float* out = (float*)d_out;

  char* p = (char*)d_ws;
  auto take = [&](size_t bytes) { char* r = p; p += (bytes + 255) & ~(size_t)255; return r; };
  unsigned short* PBUF = (unsigned short*)take((size_t)16 * 2 * 32 * HH * 2);  // 1 MB
  unsigned short* HBUF = (unsigned short*)take((size_t)16 * 2 * 32 * HH * 2);  // 1 MB
  unsigned int*   BARp = (unsigned int*)take(16 * 256);                        // 4 KB

  hipMemsetAsync(BARp, 0, 16 * 256, stream);

  k_seq<<<dim3(256), dim3(256), 0, stream>>>(
      x, xl, mk, de, xm, Wz, bz, Wr, br, Wn, bn,
      Wgx, bgx, Wgh, bgh, PBUF, HBUF, BARp, out);

  (void)in_sizes; (void)n_in; (void)out_size; (void)ws_size;
}